// Round 2
// baseline (161.323 us; speedup 1.0000x reference)
//
#include <hip/hip_runtime.h>
#include <hip/hip_bf16.h>

// FlowNetC correlation via bf16 MFMA, fp32 accumulate.
// out[b, r*21+dx, y, x] = (1/256) * sum_c in1[b,c,y,x] * in2[b,c, y+2r-20, x+2dx-20]
//
// Round-6 structure:
//  1) conv_in2 prepass (LDS-free): in2 fp32 -> in2t bf16 frag-native chunks
//     [b][y][c8=c/8][x][c%8]; thread owns (c8,x): 8 strided scalar reads
//     (256B/instr coalesced), one contiguous uint4 store (1KB/instr).
//  2) corr_mfma: block = (b, y-pair {y0,y0+2}), 16 waves, 1 block/CU.
//     NEW: in2t row (32KB) staged ONCE into LDS via global_load_lds
//     (double-buffered, issued one iter ahead), B-frags via ds_read_b128.
//     Round-5 loaded each row 4x redundantly from L2 (16 waves x 8KB =
//     128KB/iter/CU -> 720MB L2 traffic ~ 21us); staging cuts L2 reads 4x
//     and replaces them with conflict-free LDS reads. vmcnt(0)+lgkmcnt(0)
//     before the single per-iter barrier: stage issued at iter TOP, so the
//     drain is ~free (no counted-vmcnt fragility from variable store counts).

typedef short    bf16x8 __attribute__((ext_vector_type(8)));
typedef float    f32x4  __attribute__((ext_vector_type(4)));

constexpr int CSTRIDE = 64 * 64;        // fp32 channel plane
constexpr int BSTRIDE = 256 * CSTRIDE;  // fp32 batch

union BF2 { __hip_bfloat162 h; unsigned u; };

__device__ inline unsigned pack_bf2(float lo, float hi) {
    BF2 cv;
    cv.h = __float22bfloat162_rn(make_float2(lo, hi));
    return cv.u;
}

// ---------------- prepass: in2 -> bf16 frag-native chunks ----------------
__global__ __launch_bounds__(256)
void conv_in2(const float* __restrict__ in2, uint4* __restrict__ out16)
{
    const int tid = threadIdx.x;
    const int b = blockIdx.x & 7;
    const int y = blockIdx.x >> 3;
    const float* src = in2 + b * BSTRIDE + y * 64;            // + c*4096 + x
    uint4* dst = out16 + (b * 64 + y) * 2048;                 // 32 KB per (b,y)
#pragma unroll
    for (int it = 0; it < 8; ++it) {
        const int t  = tid + 256 * it;    // (c8, x) item
        const int c8 = t >> 6;            // 0..31
        const int x  = t & 63;
        const float* p = src + c8 * 8 * CSTRIDE + x;
        float v[8];
#pragma unroll
        for (int j = 0; j < 8; ++j) v[j] = p[j * CSTRIDE];
        uint4 o;
        o.x = pack_bf2(v[0], v[1]);
        o.y = pack_bf2(v[2], v[3]);
        o.z = pack_bf2(v[4], v[5]);
        o.w = pack_bf2(v[6], v[7]);
        dst[c8 * 64 + x] = o;
    }
}

// ---------------- main correlation kernel ----------------
__device__ inline void stage64(const uint4* __restrict__ gsrc, uint4* lds_dst) {
    // 64 lanes x 16B: global per-lane src -> LDS wave-uniform base + lane*16
    __builtin_amdgcn_global_load_lds(
        (const __attribute__((address_space(1))) void*)gsrc,
        (__attribute__((address_space(3))) void*)lds_dst,
        16, 0, 0);
}

__global__ __launch_bounds__(1024, 4)
void corr_mfma(const float* __restrict__ in1,
               const uint4* __restrict__ in2t,
               float* __restrict__ out)
{
    __shared__ __align__(16) uint4 rowbuf[2][2048];   // 64 KB: in2t row dbuf
    __shared__ float slds[2][2][21 * 65];             // 21.8 KB epilogue dbuf
    __shared__ __align__(16) uint4 zchunk;            // zero B-frag for OOB x

    const int tid  = threadIdx.x;
    const int lane = tid & 63;
    const int w    = tid >> 6;          // wave 0..15
    const int cl   = lane & 15;         // MFMA m/n lane index
    const int q    = lane >> 4;         // MFMA quad
    const int m    = w & 3;             // M-tile: gx in [16m, 16m+16)
    const int n    = m + (w >> 2);      // N-tile: col in [16n, 16n+16), n in 0..6
    const int b    = blockIdx.x & 7;    // batch -> XCD affinity
    const int p    = blockIdx.x >> 3;   // 0..31
    const int y0   = 4 * (p >> 1) + (p & 1);   // pair (y0, y0+2), covers all y

    if (tid == 0) { uint4 z = {0u, 0u, 0u, 0u}; zchunk = z; }

    // ---- A fragments for both y's: af[h][k] = in1[b, 32k+8q+j, y0+2h, 16m+cl] ----
    bf16x8 af[2][8];
#pragma unroll
    for (int h = 0; h < 2; ++h) {
        const float* pb = in1 + b * BSTRIDE + (y0 + 2 * h) * 64 + 16 * m + cl
                        + 8 * q * CSTRIDE;
#pragma unroll
        for (int k = 0; k < 8; ++k) {
            const float* pp = pb + 32 * k * CSTRIDE;
            float v[8];
#pragma unroll
            for (int j = 0; j < 8; ++j) v[j] = pp[j * CSTRIDE];
#pragma unroll
            for (int j = 0; j < 4; ++j)
                ((unsigned*)&af[h][k])[j] = pack_bf2(v[2 * j], v[2 * j + 1]);
        }
    }

    const int  x    = 16 * n + cl - 20;              // W col -> in2 x (may be OOB)
    const bool xok  = (x >= 0) && (x < 64);
    const int  gcol = 16 * n + cl;

    // ---- prologue: stage row for iter 0 (if valid), publish ----
    {
        const int yy0 = y0 - 20;
        if (yy0 >= 0) {                              // yy0 <= 41 < 64 always
            const uint4* rp = in2t + (b * 64 + yy0) * 2048;
            const int c0 = w * 128 + lane;
            stage64(rp + c0,      &rowbuf[0][w * 128]);
            stage64(rp + c0 + 64, &rowbuf[0][w * 128 + 64]);
        }
    }
    __builtin_amdgcn_sched_barrier(0);
    asm volatile("s_waitcnt vmcnt(0) lgkmcnt(0)" ::: "memory");
    __builtin_amdgcn_s_barrier();
    __builtin_amdgcn_sched_barrier(0);

    for (int i = 0; i < 22; ++i) {
        const int  ib      = i & 1;
        const int  yy      = y0 - 20 + 2 * i;
        const bool compute = (yy >= 0) && (yy < 64);

        // A: stage row for iter i+1 (issued at iter top -> latency hidden
        //    under this iter's ds_read+MFMA; drained by vmcnt(0) at W)
        {
            const int yn = y0 - 20 + 2 * (i + 1);
            if ((i + 1) < 22 && yn >= 0 && yn < 64) {
                const uint4* rp = in2t + (b * 64 + yn) * 2048;
                const int c0 = w * 128 + lane;
                stage64(rp + c0,      &rowbuf[ib ^ 1][w * 128]);
                stage64(rp + c0 + 64, &rowbuf[ib ^ 1][w * 128 + 64]);
            }
        }

        // B: compute from LDS row
        if (compute) {
            f32x4 acc0 = {0.f, 0.f, 0.f, 0.f};
            f32x4 acc1 = {0.f, 0.f, 0.f, 0.f};
            const uint4* rbase = &rowbuf[ib][q * 64 + x];
#pragma unroll
            for (int k = 0; k < 8; ++k) {
                const uint4* pk = xok ? (rbase + k * 256) : &zchunk;
                const bf16x8 bf = __builtin_bit_cast(bf16x8, *pk);
                acc0 = __builtin_amdgcn_mfma_f32_16x16x32_bf16(af[0][k], bf, acc0, 0, 0, 0);
                acc1 = __builtin_amdgcn_mfma_f32_16x16x32_bf16(af[1][k], bf, acc1, 0, 0, 0);
            }
            // diagonal gather: D[row=4q+i4][col=cl]; gx = 16m+4q+i4, d2 = gcol-gx
#pragma unroll
            for (int i4 = 0; i4 < 4; ++i4) {
                const int gx = 16 * m + 4 * q + i4;
                const int d2 = gcol - gx;
                if (d2 >= 0 && d2 <= 40 && !(d2 & 1)) {
                    slds[ib][0][(d2 >> 1) * 65 + gx] = acc0[i4];
                    slds[ib][1][(d2 >> 1) * 65 + gx] = acc1[i4];
                }
            }
        }

        // W+D: publish stage(i+1) and slds scatter; single barrier per iter.
        // vmcnt(0) is cheap: stage was issued a full compute-phase ago, and
        // prev-iter stores have had ~2 phases to retire.
        __builtin_amdgcn_sched_barrier(0);
        asm volatile("s_waitcnt vmcnt(0) lgkmcnt(0)" ::: "memory");
        __builtin_amdgcn_s_barrier();
        __builtin_amdgcn_sched_barrier(0);

        // E: half0 -> (y0, r=i), half1 -> (y0+2, r=i-1); coalesced stores
        const int r0 = i, r1 = i - 1;
#pragma unroll
        for (int t3 = 0; t3 < 3; ++t3) {
            const int t = tid + 1024 * t3;
            if (t < 2 * 21 * 64) {
                const int h  = (t >= 1344) ? 1 : 0;
                const int u  = t - 1344 * h;
                const int dx = u >> 6, gx = u & 63;
                const int r  = h ? r1 : r0;
                if (r >= 0 && r <= 20) {
                    const float val = compute ? slds[ib][h][dx * 65 + gx] * (1.f / 256.f)
                                              : 0.f;
                    out[((b * 441 + r * 21 + dx) * 64 + y0 + 2 * h) * 64 + gx] = val;
                }
            }
        }
        // no trailing barrier: iter i+1 scatters slds[ib^1]; slds[ib] reuse
        // at iter i+2 is fenced by the barrier inside iter i+1 (lgkmcnt(0)
        // covers this iter's epilogue ds_reads).
    }
}

extern "C" void kernel_launch(void* const* d_in, const int* in_sizes, int n_in,
                              void* d_out, int out_size, void* d_ws, size_t ws_size,
                              hipStream_t stream) {
    const float* in1 = (const float*)d_in[0];
    const float* in2 = (const float*)d_in[1];
    float* out = (float*)d_out;

    conv_in2<<<dim3(512), dim3(256), 0, stream>>>(in2, (uint4*)d_ws);
    corr_mfma<<<dim3(256), dim3(1024), 0, stream>>>(in1, (const uint4*)d_ws, out);
}